// Round 16
// baseline (346.757 us; speedup 1.0000x reference)
//
#include <hip/hip_runtime.h>
#include <hip/hip_bf16.h>

// R-GCN layer (fp32 in/out): out = relu(agg0/deg0 @ W0 + agg1/deg1 @ W1 + x @ Wl + b)
// Round 22: fusion v2 (agg+gemm in one kernel), occupancy-fixed vs r17:
//  - 128T blocks, 32-row output tiles (grid 2*NBH=3126; each block takes one
//    half of a 64-row bucket). LDS ~13KB -> 12 blocks/CU (r17 was 24.6KB/6).
//  - CSR build = r21 flat predicated stripe scan + half filter; gather =
//    proven depth-3 half-wave pipeline; MFMA frag code = proven gemm.
//  - aggb deleted (-100MB traffic), one launch deleted.
//  - front = r21 champion (striped reserve) with p-space on Npad=100032.
//
// ws: wb ushort[12*8*64*8] | binned uint[NB*CAPB] | xb bf16[(N+1)*128] | cursor int[8*NB]
// Requires N <= 131072 (src packed into 17 bits).

#define DFEAT 128
#define CH2 4096         // edges per bin block -> nbin=782
#define PSH 6            // bucket = 64 dst nodes
#define NBMAX 3200       // max buckets = 2*Npad/64
#define KSUB 8           // reserve stripes per bucket
#define CAPS 192         // capacity per (bucket,stripe): mean 128, +5.7 sigma
#define CAPB 1536        // = KSUB*CAPS per bucket
#define EBUFN 1024       // half-bucket CSR capacity (mean 512, +22 sigma)
#define NPACK 24         // pack_b blocks

typedef __attribute__((ext_vector_type(8))) short short8v;       // 8 bf16 (4 VGPRs)
typedef __attribute__((ext_vector_type(4))) float float4v;       // 4 fp32
typedef __attribute__((ext_vector_type(2))) unsigned int u2v;    // 8B
typedef __attribute__((ext_vector_type(4))) unsigned short ushort4v;

// Fused front: blocks [0,nbin) bin edges into striped bucket regions (p-space
// uses the PADDED relation offset Np), [nbin,nbin+NPACK) pack W, rest convert.
__global__ __launch_bounds__(256) void front_kernel(
        const float4v* __restrict__ x4, ushort4v* __restrict__ xb4, int n4,
        const int* __restrict__ src0, const int* __restrict__ dst0,
        const int* __restrict__ src1, const int* __restrict__ dst1,
        int* __restrict__ cursor, unsigned* __restrict__ binned,
        const float* __restrict__ wrel, const float* __restrict__ wloop,
        unsigned short* __restrict__ wb,
        int Np, int E, int NB, int nbin) {
    __shared__ unsigned cntp[NBMAX / 2];   // packed ushort-pair counts (6.4KB)
    __shared__ int base[NBMAX];            // 12.8KB
    int tid = threadIdx.x;
    int bid = blockIdx.x;

    if (bid < nbin) {
        // ---- bin section: block-staged counting scatter, striped reserve ----
        auto ldp = [&](int i) {            // bucket-space dst id p = r*Np + t
            int r = (i >= E) ? 1 : 0;
            int e = i - r * E;
            int t = r ? dst1[e] : dst0[e];
            return r * Np + t;
        };
        auto lds_ = [&](int i) {           // src node
            int r = (i >= E) ? 1 : 0;
            int e = i - r * E;
            return r ? src1[e] : src0[e];
        };
        int k = bid & (KSUB - 1);
        for (int i = tid; i < NBMAX / 2; i += 256) cntp[i] = 0;
        __syncthreads();
        int lo = bid * CH2, hi = min(2 * E, lo + CH2);
        // pass 1: local histogram, 4 independent loads per iteration
        for (int ii = lo + tid; ii < hi; ii += 1024) {
            int p0 = ldp(ii);
            int p1 = (ii + 256 < hi) ? ldp(ii + 256) : -1;
            int p2 = (ii + 512 < hi) ? ldp(ii + 512) : -1;
            int p3 = (ii + 768 < hi) ? ldp(ii + 768) : -1;
            int b0 = p0 >> PSH;
            atomicAdd(&cntp[b0 >> 1], (b0 & 1) ? 0x10000u : 1u);
            if (p1 >= 0) { int b1 = p1 >> PSH; atomicAdd(&cntp[b1 >> 1], (b1 & 1) ? 0x10000u : 1u); }
            if (p2 >= 0) { int b2 = p2 >> PSH; atomicAdd(&cntp[b2 >> 1], (b2 & 1) ? 0x10000u : 1u); }
            if (p3 >= 0) { int b3 = p3 >> PSH; atomicAdd(&cntp[b3 >> 1], (b3 & 1) ? 0x10000u : 1u); }
        }
        __syncthreads();
        // bulk-reserve one contiguous run per (block,bucket) in stripe k
        for (int b = tid; b < NBMAX; b += 256) {
            int c = (int)((cntp[b >> 1] >> ((b & 1) * 16)) & 0xFFFFu);
            if (c) base[b] = b * CAPB + k * CAPS + atomicAdd(&cursor[k * NB + b], c);
        }
        __syncthreads();
        // pass 2: scatter into runs; 4 independent edge loads per iteration
        for (int ii = lo + tid; ii < hi; ii += 1024) {
            int p0 = ldp(ii);             int s0 = lds_(ii);
            int i1 = ii + 256, i2 = ii + 512, i3 = ii + 768;
            int p1 = (i1 < hi) ? ldp(i1) : -1;  int s1 = (i1 < hi) ? lds_(i1) : 0;
            int p2 = (i2 < hi) ? ldp(i2) : -1;  int s2 = (i2 < hi) ? lds_(i2) : 0;
            int p3 = (i3 < hi) ? ldp(i3) : -1;  int s3 = (i3 < hi) ? lds_(i3) : 0;
            { int slot = atomicAdd(&base[p0 >> PSH], 1);
              binned[slot] = ((unsigned)(p0 & 63) << 17) | (unsigned)s0; }
            if (p1 >= 0) { int slot = atomicAdd(&base[p1 >> PSH], 1);
                           binned[slot] = ((unsigned)(p1 & 63) << 17) | (unsigned)s1; }
            if (p2 >= 0) { int slot = atomicAdd(&base[p2 >> PSH], 1);
                           binned[slot] = ((unsigned)(p2 & 63) << 17) | (unsigned)s2; }
            if (p3 >= 0) { int slot = atomicAdd(&base[p3 >> PSH], 1);
                           binned[slot] = ((unsigned)(p3 & 63) << 17) | (unsigned)s3; }
        }
    } else if (bid < nbin + NPACK) {
        // ---- pack_b section ----
        int t = (bid - nbin) * 256 + tid;    // 0..6143
        if (t < 12 * 8 * 64) {
            int lane = t & 63;
            int kbase = (t >> 9) * 32 + (lane >> 4) * 8;
            int col = (((t >> 6) & 7) << 4) + (lane & 15);
            unsigned short tmp[8];
#pragma unroll
            for (int j = 0; j < 8; ++j) {
                int kk = kbase + j;
                float v = (kk < 256) ? wrel[kk * DFEAT + col]
                                     : wloop[(kk - 256) * DFEAT + col];
                tmp[j] = __hip_bfloat16_raw(__float2bfloat16(v)).x;
            }
            *(ushort4*)(wb + t * 8)     = make_ushort4(tmp[0], tmp[1], tmp[2], tmp[3]);
            *(ushort4*)(wb + t * 8 + 4) = make_ushort4(tmp[4], tmp[5], tmp[6], tmp[7]);
        }
    } else {
        // ---- convert section: 4 coalesced float4 per thread (64B) ----
        int cb = bid - nbin - NPACK;
#pragma unroll
        for (int kk = 0; kk < 4; ++kk) {
            int i = cb * 1024 + kk * 256 + tid;
            if (i < n4) {
                float4v v = __builtin_nontemporal_load(x4 + i);
                ushort4v o;
                o[0] = __hip_bfloat16_raw(__float2bfloat16(v[0])).x;
                o[1] = __hip_bfloat16_raw(__float2bfloat16(v[1])).x;
                o[2] = __hip_bfloat16_raw(__float2bfloat16(v[2])).x;
                o[3] = __hip_bfloat16_raw(__float2bfloat16(v[3])).x;
                xb4[i] = o;
            }
        }
    }
}

#define CONSUME(Q0, Q1, Q2, Q3) {                                              \
    a[0] += __uint_as_float(Q0[0] << 16) + __uint_as_float(Q1[0] << 16)        \
          + __uint_as_float(Q2[0] << 16) + __uint_as_float(Q3[0] << 16);       \
    a[1] += __uint_as_float(Q0[0] & 0xffff0000u) + __uint_as_float(Q1[0] & 0xffff0000u) \
          + __uint_as_float(Q2[0] & 0xffff0000u) + __uint_as_float(Q3[0] & 0xffff0000u); \
    a[2] += __uint_as_float(Q0[1] << 16) + __uint_as_float(Q1[1] << 16)        \
          + __uint_as_float(Q2[1] << 16) + __uint_as_float(Q3[1] << 16);       \
    a[3] += __uint_as_float(Q0[1] & 0xffff0000u) + __uint_as_float(Q1[1] & 0xffff0000u) \
          + __uint_as_float(Q2[1] & 0xffff0000u) + __uint_as_float(Q3[1] & 0xffff0000u); }

// Fused aggregation + GEMM. One 128T block per 32-row output tile g.
// Tile g = half (g&1) of bucket (g>>1); rel1 buckets offset by NBH.
// Per rel: CSR (flat stripe scan + half filter) -> depth-3 half-wave gather
// -> bf16 rows into Atile -> 4 MFMA k-chunks. Then self-loop + epilogue.
__global__ __launch_bounds__(128) void aggmm_kernel(
        const u2v* __restrict__ xb2,          // x bf16 rows as u2v[N][32]
        const unsigned short* __restrict__ xb,
        const unsigned* __restrict__ binned,
        const int* __restrict__ cursor,
        const unsigned short* __restrict__ wb,
        const float* __restrict__ bias,
        float* __restrict__ out, int N, int NB, int NBH) {
    __shared__ unsigned ebuf[EBUFN];                        // 4KB
    __shared__ __align__(16) unsigned short Atile[32][136]; // 8.7KB
    __shared__ int cnt[32], cur[32], rs[32];
    __shared__ int scnt[KSUB];
    int tid = threadIdx.x;
    int g = blockIdx.x;
    int bb = g >> 1, hf = g & 1;
    int hw = tid >> 5, lane = tid & 31;   // 4 half-waves (gather)
    int wv = tid >> 6, l64 = tid & 63;    // 2 waves (MFMA)
    int mrow = l64 & 15, quad = l64 >> 4;

    float4v acc[8];
#pragma unroll
    for (int ct = 0; ct < 8; ++ct) acc[ct] = (float4v){0.f, 0.f, 0.f, 0.f};

    for (int rel = 0; rel < 2; ++rel) {
        int b = rel * NBH + bb;
        const unsigned* seg = binned + (size_t)b * CAPB;

        if (tid < 32) cnt[tid] = 0;
        if (tid < KSUB) scnt[tid] = min(cursor[tid * NB + b], CAPS);
        __syncthreads();
        // hist: flat predicated stripe scan, keep only this half's p's
        for (int i = tid; i < CAPB; i += 128) {
            int k = (i * 683) >> 17;      // i / 192
            if (i - k * CAPS < scnt[k]) {
                unsigned v = seg[i];
                int p6 = (int)(v >> 17) & 63;
                if ((p6 >> 5) == hf) atomicAdd(&cnt[p6 & 31], 1);
            }
        }
        __syncthreads();
        if (tid < 32) {
            int c = cnt[tid];
            int inc = c;
#pragma unroll
            for (int off = 1; off < 32; off <<= 1) {
                int t2 = __shfl_up(inc, off);
                if (tid >= off) inc += t2;
            }
            rs[tid] = inc - c;
            cur[tid] = inc - c;
        }
        __syncthreads();
        // counting-scatter into LDS CSR
        for (int i = tid; i < CAPB; i += 128) {
            int k = (i * 683) >> 17;
            if (i - k * CAPS < scnt[k]) {
                unsigned v = seg[i];
                int p6 = (int)(v >> 17) & 63;
                if ((p6 >> 5) == hf) {
                    int slot = atomicAdd(&cur[p6 & 31], 1);
                    if (slot < EBUFN) ebuf[slot] = v & 0x1FFFFu;
                }
            }
        }
        __syncthreads();

        // gather: 4 half-waves x 8 p's; depth-3 rolling pipeline
        for (int pi = 0; pi < 8; ++pi) {
            int pl = hw * 8 + pi;
            int s0 = rs[pl];
            int c = cnt[pl];
            if (s0 >= EBUFN) c = 0; else c = min(c, EBUFN - s0);
            float4v a = (float4v){0.f, 0.f, 0.f, 0.f};
            int e = 0;
            if (c >= 8) {
                u2v A0 = xb2[(size_t)ebuf[s0]     * 32 + lane];
                u2v B0 = xb2[(size_t)ebuf[s0 + 1] * 32 + lane];
                u2v C0 = xb2[(size_t)ebuf[s0 + 2] * 32 + lane];
                u2v D0 = xb2[(size_t)ebuf[s0 + 3] * 32 + lane];
                u2v A1 = xb2[(size_t)ebuf[s0 + 4] * 32 + lane];
                u2v B1 = xb2[(size_t)ebuf[s0 + 5] * 32 + lane];
                u2v C1 = xb2[(size_t)ebuf[s0 + 6] * 32 + lane];
                u2v D1 = xb2[(size_t)ebuf[s0 + 7] * 32 + lane];
                for (e = 8; e + 4 <= c; e += 4) {
                    u2v nA = xb2[(size_t)ebuf[s0 + e]     * 32 + lane];
                    u2v nB = xb2[(size_t)ebuf[s0 + e + 1] * 32 + lane];
                    u2v nC = xb2[(size_t)ebuf[s0 + e + 2] * 32 + lane];
                    u2v nD = xb2[(size_t)ebuf[s0 + e + 3] * 32 + lane];
                    CONSUME(A0, B0, C0, D0);
                    A0 = A1; B0 = B1; C0 = C1; D0 = D1;
                    A1 = nA; B1 = nB; C1 = nC; D1 = nD;
                }
                CONSUME(A0, B0, C0, D0);
                CONSUME(A1, B1, C1, D1);
            } else if (c >= 4) {
                u2v A0 = xb2[(size_t)ebuf[s0]     * 32 + lane];
                u2v B0 = xb2[(size_t)ebuf[s0 + 1] * 32 + lane];
                u2v C0 = xb2[(size_t)ebuf[s0 + 2] * 32 + lane];
                u2v D0 = xb2[(size_t)ebuf[s0 + 3] * 32 + lane];
                CONSUME(A0, B0, C0, D0);
                e = 4;
            }
            for (; e < c; ++e) {
                int s = ebuf[s0 + e];
                u2v gq = xb2[(size_t)s * 32 + lane];
                a[0] += __uint_as_float(gq[0] << 16);
                a[1] += __uint_as_float(gq[0] & 0xffff0000u);
                a[2] += __uint_as_float(gq[1] << 16);
                a[3] += __uint_as_float(gq[1] & 0xffff0000u);
            }
            float inv = 1.0f / (float)max(c, 1);
            ushort4v w;
            w[0] = __hip_bfloat16_raw(__float2bfloat16(a[0] * inv)).x;
            w[1] = __hip_bfloat16_raw(__float2bfloat16(a[1] * inv)).x;
            w[2] = __hip_bfloat16_raw(__float2bfloat16(a[2] * inv)).x;
            w[3] = __hip_bfloat16_raw(__float2bfloat16(a[3] * inv)).x;
            *(ushort4v*)&Atile[pl][4 * lane] = w;
        }
        __syncthreads();

        // MFMA k-chunks for this relation (A from Atile)
#pragma unroll
        for (int kc4 = 0; kc4 < 4; ++kc4) {
            int kc = rel * 4 + kc4;
            short8v a0 = *(const short8v*)&Atile[wv * 16 + mrow][kc4 * 32 + quad * 8];
#pragma unroll
            for (int ct = 0; ct < 8; ++ct) {
                short8v bfr = *(const short8v*)(wb + (((kc * 8 + ct) << 6) + l64) * 8);
                acc[ct] = __builtin_amdgcn_mfma_f32_16x16x32_bf16(a0, bfr, acc[ct], 0, 0, 0);
            }
        }
        __syncthreads();   // before next rel reuses cnt/ebuf/Atile
    }

    // self-loop k-chunks straight from xb (global, streaming)
    int n0 = min(g * 32 + wv * 16 + mrow, N - 1);
#pragma unroll
    for (int kc = 8; kc < 12; ++kc) {
        short8v a0 = *(const short8v*)(xb + (size_t)n0 * DFEAT + (kc & 3) * 32 + quad * 8);
#pragma unroll
        for (int ct = 0; ct < 8; ++ct) {
            short8v bfr = *(const short8v*)(wb + (((kc * 8 + ct) << 6) + l64) * 8);
            acc[ct] = __builtin_amdgcn_mfma_f32_16x16x32_bf16(a0, bfr, acc[ct], 0, 0, 0);
        }
    }

    // epilogue: bias + relu + store
#pragma unroll
    for (int ct = 0; ct < 8; ++ct) {
        int col = ct * 16 + mrow;
        float bv = bias[col];
#pragma unroll
        for (int i = 0; i < 4; ++i) {
            int row = g * 32 + wv * 16 + quad * 4 + i;
            if (row < N)
                __builtin_nontemporal_store(fmaxf(acc[ct][i] + bv, 0.f),
                                            out + (size_t)row * DFEAT + col);
        }
    }
}

extern "C" void kernel_launch(void* const* d_in, const int* in_sizes, int n_in,
                              void* d_out, int out_size, void* d_ws, size_t ws_size,
                              hipStream_t stream) {
    const float* x      = (const float*)d_in[0];
    const int* src_fwd  = (const int*)d_in[1];
    const int* dst_fwd  = (const int*)d_in[2];
    const int* src_bwd  = (const int*)d_in[3];
    const int* dst_bwd  = (const int*)d_in[4];
    const float* wrel   = (const float*)d_in[5];
    const float* wloop  = (const float*)d_in[6];
    const float* hbias  = (const float*)d_in[7];
    float* out          = (float*)d_out;

    int N = in_sizes[0] / DFEAT;
    int E = in_sizes[1];
    int TE = 2 * E;
    int Npad = (N + 63) & ~63;       // 100032 (64-aligned relation offset)
    int NBH = Npad >> 6;             // 1563 buckets per relation
    int NB = 2 * NBH;                // 3126 buckets total

    unsigned short* wb   = (unsigned short*)d_ws;                        // 96KB
    unsigned* binned     = (unsigned*)(wb + 12 * 8 * 64 * 8);            // [NB*CAPB] = 19.2MB
    unsigned short* xb   = (unsigned short*)(binned + (size_t)NB * CAPB);// [(N+1)*128]
    int* cursor          = (int*)(xb + (size_t)(N + 1) * DFEAT);         // [8*NB]

    int n4 = N * (DFEAT / 4);
    int nconv = (n4 + 1023) / 1024;    // 3125
    int nbin = (TE + CH2 - 1) / CH2;   // 782

    (void)hipMemsetAsync(cursor, 0, KSUB * NB * sizeof(int), stream);

    front_kernel<<<nbin + NPACK + nconv, 256, 0, stream>>>(
        (const float4v*)x, (ushort4v*)xb, n4,
        src_fwd, dst_fwd, src_bwd, dst_bwd,
        cursor, binned, wrel, wloop, wb, Npad, E, NB, nbin);

    aggmm_kernel<<<2 * NBH, 128, 0, stream>>>(
        (const u2v*)xb, xb, binned, cursor, wb, hbias, out, N, NB, NBH);
}